// Round 9
// baseline (701.022 us; speedup 1.0000x reference)
//
#include <hip/hip_runtime.h>
#include <stdint.h>

#define NB 32
#define SEQ 128
#define EMB 128
#define NSTEP 127
#define NS 512
#define NBLK 512
#define NUNIT 4064   // NB*NSTEP

__device__ __forceinline__ float ftanh(float x){ float e=__expf(2.f*x); return 1.f-2.f/(e+1.f); }
__device__ __forceinline__ float fsig(float x){ return 1.f/(1.f+__expf(-x)); }
__device__ __forceinline__ float4 ld4(const float* p){ return *(const float4*)p; }

// ---------------------------------------------------------------------------
// Streamed-WT GEMM, 8 rows (identical to round-8 proven version).
// NAMED register double groups only — any VGPR array with non-constant index
// is demoted to scratch (round 5/6: 256 VGPR + 554 MB scratch traffic).
// ---------------------------------------------------------------------------
#define FMA4(acc, xv, a0, a1, a2, a3) \
  acc.x = fmaf(xv.x, a0.x, fmaf(xv.y, a1.x, fmaf(xv.z, a2.x, fmaf(xv.w, a3.x, acc.x)))); \
  acc.y = fmaf(xv.x, a0.y, fmaf(xv.y, a1.y, fmaf(xv.z, a2.y, fmaf(xv.w, a3.y, acc.y)))); \
  acc.z = fmaf(xv.x, a0.z, fmaf(xv.y, a1.z, fmaf(xv.z, a2.z, fmaf(xv.w, a3.z, acc.z)))); \
  acc.w = fmaf(xv.x, a0.w, fmaf(xv.y, a1.w, fmaf(xv.z, a2.w, fmaf(xv.w, a3.w, acc.w))));

template<int K, int XS>
__device__ __forceinline__ void gemm8(const float* __restrict__ WT, int NEtot,
                                      const float* Xl, const float* __restrict__ bias,
                                      float* outb /*[8][132]*/)
{
  const int tid = threadIdx.x;
  const int et = tid & 31;
  const int rt = tid >> 5;
  const float* wp = WT + et*4;
  const float* xr = Xl + rt*XS;
  constexpr int G = K/4;
  float4 acc = {0.f,0.f,0.f,0.f};
  float4 w0 = ld4(wp);
  float4 w1 = ld4(wp + NEtot);
  float4 w2 = ld4(wp + 2*NEtot);
  float4 w3 = ld4(wp + 3*NEtot);
  const float* wq = wp + (size_t)4*NEtot;
  float4 m0 = ld4(wq);
  float4 m1 = ld4(wq + NEtot);
  float4 m2 = ld4(wq + 2*NEtot);
  float4 m3 = ld4(wq + 3*NEtot);
  #pragma unroll 2
  for (int g = 0; g + 2 < G; g += 2) {
    const float* wa = wp + (size_t)(4*(g+2))*NEtot;
    float4 n0 = ld4(wa);
    float4 n1 = ld4(wa + NEtot);
    float4 n2 = ld4(wa + 2*NEtot);
    float4 n3 = ld4(wa + 3*NEtot);
    float4 xa = ld4(xr + 4*g);
    FMA4(acc, xa, w0, w1, w2, w3);
    w0=n0; w1=n1; w2=n2; w3=n3;
    const float* wb = wp + (size_t)(4*(g+3))*NEtot;
    float4 o0 = ld4(wb);
    float4 o1 = ld4(wb + NEtot);
    float4 o2 = ld4(wb + 2*NEtot);
    float4 o3 = ld4(wb + 3*NEtot);
    float4 xb = ld4(xr + 4*(g+1));
    FMA4(acc, xb, m0, m1, m2, m3);
    m0=o0; m1=o1; m2=o2; m3=o3;
  }
  {
    float4 xa = ld4(xr + 4*(G-2));
    FMA4(acc, xa, w0, w1, w2, w3);
    float4 xb = ld4(xr + 4*(G-1));
    FMA4(acc, xb, m0, m1, m2, m3);
  }
  float4 bb = ld4(bias + et*4);
  acc.x+=bb.x; acc.y+=bb.y; acc.z+=bb.z; acc.w+=bb.w;
  *(float4*)(outb + rt*132 + et*4) = acc;
}

__device__ __forceinline__ float wredsum(float v) {
  #pragma unroll
  for (int o = 32; o > 0; o >>= 1) v += __shfl_down(v, o);
  return v;
}
__device__ __forceinline__ float wredmax(float v) {
  #pragma unroll
  for (int o = 32; o > 0; o >>= 1) v = fmaxf(v, __shfl_down(v, o));
  return v;
}

// Device-scope grid barrier. bar pre-zeroed by k_zero each launch.
// All NBLK blocks are co-resident (launch_bounds(256,2) -> >=2 blocks/CU).
__device__ __forceinline__ void gsync(int* bar, int idx, int nb) {
  __syncthreads();
  if (threadIdx.x == 0) {
    __threadfence();
    int prev = __hip_atomic_fetch_add(&bar[idx*32], 1, __ATOMIC_ACQ_REL,
                                      __HIP_MEMORY_SCOPE_AGENT);
    if (prev == nb - 1) {
      __hip_atomic_store(&bar[idx*32 + 16], 1, __ATOMIC_RELEASE,
                         __HIP_MEMORY_SCOPE_AGENT);
    } else {
      while (__hip_atomic_load(&bar[idx*32 + 16], __ATOMIC_ACQUIRE,
                               __HIP_MEMORY_SCOPE_AGENT) == 0)
        __builtin_amdgcn_s_sleep(8);
    }
    __threadfence();
  }
  __syncthreads();
}

__global__ void k_zero(int* __restrict__ bar, int* __restrict__ Pmaxi) {
  int i = threadIdx.x;
  if (i < 128) bar[i] = 0;
  if (i < 128) Pmaxi[i] = 0;
}

// ---------------------------------------------------------------------------
// k_fused: P0 transposes+misc+match | P1 k_pre | P2 k_pre2 | P3 k_chain |
//          P4 k_attn (2 units/iteration). Grid barriers between phases.
// ---------------------------------------------------------------------------
__global__ __launch_bounds__(256, 2) void k_fused(
    const int* __restrict__ question, const int* __restrict__ response,
    const int* __restrict__ maskp, const int* __restrict__ q_neighbors,
    const int* __restrict__ s_neighbors, const float* __restrict__ qs_table,
    const float* __restrict__ emb_q, const float* __restrict__ emb_s,
    const float* __restrict__ emb_r,
    const float* __restrict__ W_ih, const float* __restrict__ b_ih,
    const float* __restrict__ b_hh, const float* __restrict__ W_agg,
    const float* __restrict__ b_agg, const float* __restrict__ W_last,
    const float* __restrict__ b_last, const float* __restrict__ W_query,
    const float* __restrict__ b_query, const float* __restrict__ w_W,
    float* __restrict__ WT012, float* __restrict__ WLT, float* __restrict__ WQT,
    float* __restrict__ WIHT, float* __restrict__ BIH, float* __restrict__ CPAD,
    float* __restrict__ E1, float* __restrict__ G1, float* __restrict__ E2,
    float* __restrict__ Hfull, float* __restrict__ Cq,
    int* __restrict__ Pmaxi, int* __restrict__ nsel,
    unsigned long long* __restrict__ mwords, int* __restrict__ bar,
    float* __restrict__ out)
{
  __shared__ float pool[6336];   // XA|XB|M1|M2|XC overlays; P4 us2/red cells
  __shared__ int ipool[256];
  __shared__ unsigned long long wvw[4];
  float* XA = pool;
  float* XB = pool + 1056;
  float* M1 = pool + 2112;
  float* M2 = pool + 3168;
  float* XC = pool + 4224;       // 2112

  const int tid = threadIdx.x;
  const int blk = blockIdx.x;

  // ================= P0: transposes, BIH/CPAD, G1 zero, match masks ========
  {
    const int gid = blk*256 + tid;
    const int gsz = NBLK*256;
    for (int i = gid; i < 49152; i += gsz) {
      int j = i >> 14, rem = i & 16383, k = rem >> 7, e = rem & 127;
      WT012[i] = W_agg[j*16384 + e*128 + k];
    }
    for (int i = gid; i < 16384; i += gsz) {
      int k = i >> 7, e = i & 127;
      WLT[i] = W_last[e*128 + k];
      WQT[i] = W_query[e*128 + k];
    }
    for (int i = gid; i < 131072; i += gsz) {
      int k = i >> 9, e = i & 511;
      WIHT[i] = W_ih[e*256 + k];
    }
    for (int i = gid; i < 65536; i += gsz) G1[i] = 0.f;
    if (gid < 512) BIH[gid] = b_ih[gid] + b_hh[gid];
    if (blk == 0) {
      float v = (tid < 128) ? ftanh(b_query[tid]) * w_W[128 + tid] : 0.f;
      pool[tid] = v; __syncthreads();
      #pragma unroll
      for (int s = 128; s > 0; s >>= 1) {
        if (tid < s) pool[tid] += pool[tid + s];
        __syncthreads();
      }
      if (tid == 0) CPAD[0] = pool[0];
      __syncthreads();
    }
    // match masks: 8 units per block, 2 per iteration (halves)
    const int half = tid >> 7, lt = tid & 127;
    for (int it = 0; it < 4; ++it) {
      int u = blk*8 + it*2 + half;
      if (u >= NUNIT) u = NUNIT - 1;   // duplicate work, identical writes
      int b = u / NSTEP, t = u - b*NSTEP;
      const int q_next = question[b*SEQ + t + 1];
      int* qr = ipool + half*40;
      if (lt < 40)
        qr[lt] = s_neighbors[(size_t)q_neighbors[(size_t)q_next*4 + lt/10]*10 + lt%10];
      __syncthreads();
      int qp = question[b*SEQ + lt];
      bool p = false;
      #pragma unroll 8
      for (int i = 0; i < 40; ++i) p |= (qp == qr[i]);
      p &= (lt < t);
      unsigned long long bal = __ballot(p);
      if ((tid & 63) == 0) {
        mwords[((size_t)b*NSTEP + t)*2 + ((tid >> 6) & 1)] = bal;
        wvw[tid >> 6] = bal;
      }
      __syncthreads();
      if (lt == 0) {
        unsigned long long a0 = wvw[half*2], a1 = wvw[half*2 + 1];
        int ns = __popcll(a0) + __popcll(a1);
        nsel[b*NSTEP + t] = ns;
        atomicMax(&Pmaxi[t], ns);
      }
      __syncthreads();
    }
  }
  gsync(bar, 0, NBLK);

  // ================= P1: k_pre (704 units over 512 blocks) =================
  for (int u = blk; u < 704; u += NBLK) {
    int* idx = ipool;        // 80
    int* n3i = ipool + 80;   // 32
    if (u < 64) {
      const int s0 = u*8;
      if (tid < 80) idx[tid] = s_neighbors[s0*10 + tid];
      __syncthreads();
      {
        int r = tid >> 5, e4 = (tid & 31) << 2;
        float4 a = ld4(emb_s + (size_t)(s0+r)*128 + e4);
        float sx=0,sy=0,sz=0,sw=0;
        #pragma unroll
        for (int jj = 0; jj < 10; ++jj) {
          float4 q = ld4(emb_q + (size_t)idx[r*10+jj]*128 + e4);
          sx+=q.x; sy+=q.y; sz+=q.z; sw+=q.w;
        }
        float4 o; o.x=a.x+0.1f*sx; o.y=a.y+0.1f*sy; o.z=a.z+0.1f*sz; o.w=a.w+0.1f*sw;
        *(float4*)(XA + r*132 + e4) = o;
      }
      __syncthreads();
      gemm8<128,132>(WT012 + 16384, 128, XA, b_agg + 128, XB);
      __syncthreads();
      for (int f = tid; f < 1024; f += 256) {
        int r = f >> 7, e = f & 127;
        E1[(size_t)(s0+r)*128 + e] = ftanh(XB[r*132 + e]);
      }
    } else {
      const int p0 = (u-64)*8;
      if (tid < 8) idx[tid] = s_neighbors[p0 + tid];
      __syncthreads();
      if (tid < 32) n3i[tid] = q_neighbors[(size_t)idx[tid>>2]*4 + (tid&3)];
      __syncthreads();
      {
        int r = tid >> 5, e4 = (tid & 31) << 2;
        float4 a = ld4(emb_q + (size_t)idx[r]*128 + e4);
        float sx=0,sy=0,sz=0,sw=0;
        #pragma unroll
        for (int k = 0; k < 4; ++k) {
          float4 q = ld4(emb_s + (size_t)n3i[r*4+k]*128 + e4);
          sx+=q.x; sy+=q.y; sz+=q.z; sw+=q.w;
        }
        float4 o; o.x=a.x+0.25f*sx; o.y=a.y+0.25f*sy; o.z=a.z+0.25f*sz; o.w=a.w+0.25f*sw;
        *(float4*)(XA + r*132 + e4) = o;
      }
      __syncthreads();
      gemm8<128,132>(WT012 + 32768, 128, XA, b_agg + 256, XB);
      __syncthreads();
      for (int f = tid; f < 1024; f += 256) {
        int r = f >> 7, e = f & 127;
        atomicAdd(&G1[(size_t)((p0+r)/10)*128 + e], ftanh(XB[r*132 + e]));
      }
    }
    __syncthreads();
  }
  gsync(bar, 1, NBLK);

  // ================= P2: k_pre2 (64 units) =================================
  if (blk < 64) {
    const int s0 = blk*8;
    for (int f = tid; f < 1024; f += 256) {
      int r = f >> 7, e = f & 127;
      XA[r*132 + e] = 0.1f*G1[(size_t)(s0+r)*128 + e] + E1[(size_t)(s0+r)*128 + e];
    }
    __syncthreads();
    gemm8<128,132>(WT012 + 16384, 128, XA, b_agg + 128, XB);
    __syncthreads();
    for (int f = tid; f < 1024; f += 256) {
      int r = f >> 7, e = f & 127;
      E2[(size_t)(s0+r)*128 + e] = ftanh(XB[r*132 + e]);
    }
  }
  gsync(bar, 2, NBLK);

  // ================= P3: k_chain (508 units) ===============================
  if (blk < 508) {
    int* qts = ipool;        // 8
    int* rts = ipool + 8;    // 8
    int* mts = ipool + 16;   // 8
    int* n1s = ipool + 24;   // 32
    if (tid < 8) {
      int rid = blk*8 + tid;
      int b = rid / 127, t = rid - b*127;
      qts[tid] = question[b*SEQ + t];
      rts[tid] = response[b*SEQ + t];
      mts[tid] = maskp[b*SEQ + t];
    }
    __syncthreads();
    if (tid < 32) n1s[tid] = q_neighbors[(size_t)qts[tid>>2]*4 + (tid&3)];
    __syncthreads();
    {
      int r = tid >> 5, e4 = (tid & 31) << 2;
      const int* nn = n1s + r*4;
      float4 a = ld4(emb_q + (size_t)qts[r]*128 + e4);
      float s1x=0,s1y=0,s1z=0,s1w=0, s2x=0,s2y=0,s2z=0,s2w=0, s3x=0,s3y=0,s3z=0,s3w=0;
      #pragma unroll
      for (int i = 0; i < 4; ++i) {
        float4 q1 = ld4(emb_s + (size_t)nn[i]*128 + e4);
        float4 q2 = ld4(E1 + (size_t)nn[i]*128 + e4);
        float4 q3 = ld4(E2 + (size_t)nn[i]*128 + e4);
        s1x+=q1.x; s1y+=q1.y; s1z+=q1.z; s1w+=q1.w;
        s2x+=q2.x; s2y+=q2.y; s2z+=q2.z; s2w+=q2.w;
        s3x+=q3.x; s3y+=q3.y; s3z+=q3.z; s3w+=q3.w;
      }
      float4 o; o.x=a.x+0.25f*s1x; o.y=a.y+0.25f*s1y; o.z=a.z+0.25f*s1z; o.w=a.w+0.25f*s1w;
      *(float4*)(XA + r*132 + e4) = o;
      float4 p; p.x=0.25f*s2x; p.y=0.25f*s2y; p.z=0.25f*s2z; p.w=0.25f*s2w;
      *(float4*)(M1 + r*132 + e4) = p;
      float4 u; u.x=0.25f*s3x; u.y=0.25f*s3y; u.z=0.25f*s3z; u.w=0.25f*s3w;
      *(float4*)(M2 + r*132 + e4) = u;
    }
    __syncthreads();
    gemm8<128,132>(WT012, 128, XA, b_agg, XB);     // e0_1 pre-act
    __syncthreads();
    for (int f = tid; f < 1056; f += 256) XB[f] = M1[f] + ftanh(XB[f]);
    __syncthreads();
    gemm8<128,132>(WT012, 128, XB, b_agg, XA);     // e0_2 pre-act
    __syncthreads();
    for (int f = tid; f < 1056; f += 256) XA[f] = M2[f] + ftanh(XA[f]);
    __syncthreads();
    gemm8<128,132>(WT012, 128, XA, b_agg, XB);     // e0_3 pre-act
    __syncthreads();
    for (int f = tid; f < 1056; f += 256) XB[f] = ftanh(XB[f]);
    __syncthreads();
    gemm8<128,132>(WLT, 128, XB, b_last, XA);      // agg pre-act
    __syncthreads();
    for (int f = tid; f < 1024; f += 256) {
      int r = f >> 7, e = f & 127;
      float agg = ftanh(XA[r*132 + e]);
      XC[r*264 + e] = (mts[r] == 1) ? agg : emb_q[(size_t)qts[r]*128 + e];
      XC[r*264 + 128 + e] = emb_r[rts[r]*128 + e];
    }
    __syncthreads();
    gemm8<256,264>(WIHT,       512, XC, BIH,       XA);
    gemm8<256,264>(WIHT + 256, 512, XC, BIH + 256, XB);
    gemm8<256,264>(WIHT + 384, 512, XC, BIH + 384, M1);
    __syncthreads();
    for (int f = tid; f < 1024; f += 256) {
      int r = f >> 7, e = f & 127;
      float gi = XA[r*132 + e], gg = XB[r*132 + e], go = M1[r*132 + e];
      float h = fsig(go) * ftanh(fsig(gi) * ftanh(gg));
      XC[r*264 + e] = h;
      Hfull[(size_t)(blk*8 + r)*128 + e] = h;
    }
    __syncthreads();
    gemm8<128,264>(WQT, 128, XC, b_query, XA);     // c pre-act
    __syncthreads();
    {
      const int et = tid & 31, rt = tid >> 5;
      float4 o = ld4(XA + rt*132 + et*4);
      float4 wv = ld4(w_W + 128 + et*4);
      float s = ftanh(o.x)*wv.x + ftanh(o.y)*wv.y + ftanh(o.z)*wv.z + ftanh(o.w)*wv.w;
      #pragma unroll
      for (int off = 16; off > 0; off >>= 1) s += __shfl_down(s, off);
      if (et == 0) Cq[blk*8 + rt] = s;
    }
  }
  gsync(bar, 3, NBLK);

  // ================= P4: k_attn (8 units/block, 2 per iteration) ===========
  {
    const int half = tid >> 7, lt = tid & 127;
    const int widh = (tid >> 6) & 1;
    float* us = pool + half*128;          // [2][128]
    float* smx = pool + 256 + half*2;     // [2][2]
    float* s3 = pool + 260 + half*6;      // [2][2][3]
    int* cols = ipool + half*8;           // [2][8]
    int* cntp = ipool + 16 + half;        // [2]
    const float c_pad = CPAD[0];
    for (int it = 0; it < 4; ++it) {
      int u = blk*8 + it*2 + half;
      if (u >= NUNIT) u = NUNIT - 1;      // duplicate of last unit: same writes
      const int b = u / NSTEP, t = u - b*NSTEP;
      const size_t bt = (size_t)b*NSTEP + t;
      const int q_next = question[b*SEQ + t + 1];
      if (lt == 0) *cntp = 0;
      __syncthreads();
      {
        float4 v = ld4(qs_table + (size_t)q_next*NS + lt*4);
        if (v.x > 0.f) { int p = atomicAdd(cntp, 1); if (p < 8) cols[p] = lt*4; }
        if (v.y > 0.f) { int p = atomicAdd(cntp, 1); if (p < 8) cols[p] = lt*4+1; }
        if (v.z > 0.f) { int p = atomicAdd(cntp, 1); if (p < 8) cols[p] = lt*4+2; }
        if (v.w > 0.f) { int p = atomicAdd(cntp, 1); if (p < 8) cols[p] = lt*4+3; }
      }
      __syncthreads();
      const int nc = min(*cntp, 4);
      {
        float ue = emb_q[(size_t)q_next*EMB + lt];
        for (int i = 0; i < nc; ++i) ue += emb_s[(size_t)cols[i]*EMB + lt];
        us[lt] = ue;
      }
      const float P = (float)(Pmaxi[t] - nsel[bt]);
      const unsigned long long w0 = mwords[bt*2 + 0];
      const unsigned long long w1 = mwords[bt*2 + 1];
      const bool matched = (lt < 64) ? ((w0 >> lt) & 1ull)
                                     : ((w1 >> (lt - 64)) & 1ull);
      const float c_cur = Cq[bt];
      float Cp = matched ? ((lt == 0) ? c_pad : Cq[(size_t)b*NSTEP + lt]) : -3.0e38f;
      float mh = wredmax(Cp);
      if ((tid & 63) == 0) smx[widh] = mh;
      __syncthreads();   // also publishes us[]
      float M = fmaxf(fmaxf(smx[0], smx[1]), fmaxf(c_cur, c_pad));
      float wgt = matched ? __expf(Cp - M) : 0.f;
      float dotp = 0.f;
      if (matched && lt >= 1) {  // p=0 history row is zeros
        const float* hp = Hfull + ((size_t)b*NSTEP + lt)*EMB;
        float s = 0.f;
        #pragma unroll 8
        for (int e = 0; e < 128; e += 4) {
          float4 h4 = ld4(hp + e);
          s = fmaf(us[e],h4.x, fmaf(us[e+1],h4.y, fmaf(us[e+2],h4.z, fmaf(us[e+3],h4.w, s))));
        }
        dotp = s;
      }
      float gcp = us[lt] * Hfull[bt*EMB + lt];
      float a0 = wredsum(wgt);
      float a1 = wredsum(wgt * dotp);
      float a2 = wredsum(gcp);
      if ((tid & 63) == 0) { s3[widh*3+0] = a0; s3[widh*3+1] = a1; s3[widh*3+2] = a2; }
      __syncthreads();
      if (lt == 0) {
        float Sexp = s3[0] + s3[3];
        float Snum = s3[1] + s3[4];
        float gc   = s3[2] + s3[5];
        float Ec = __expf(c_cur - M), Ep = __expf(c_pad - M);
        float D = Sexp + Ec + P * Ep;
        float numt = Snum + Ec * gc;
        out[b*SEQ + t + 1] = fsig(numt / D);
        if (t == 0) out[b*SEQ] = 0.5f;
      }
      __syncthreads();
    }
  }
}

extern "C" void kernel_launch(void* const* d_in, const int* in_sizes, int n_in,
                              void* d_out, int out_size, void* d_ws, size_t ws_size,
                              hipStream_t stream) {
  const int* question    = (const int*)d_in[0];
  const int* response    = (const int*)d_in[1];
  const int* maskp       = (const int*)d_in[2];
  const int* q_neighbors = (const int*)d_in[3];
  const int* s_neighbors = (const int*)d_in[4];
  const float* qs_table  = (const float*)d_in[5];
  const float* emb_q     = (const float*)d_in[6];
  const float* emb_s     = (const float*)d_in[7];
  const float* emb_r     = (const float*)d_in[8];
  const float* W_ih      = (const float*)d_in[9];
  const float* b_ih      = (const float*)d_in[10];
  const float* b_hh      = (const float*)d_in[11];
  const float* W_agg     = (const float*)d_in[12];
  const float* b_agg     = (const float*)d_in[13];
  const float* W_last    = (const float*)d_in[14];
  const float* b_last    = (const float*)d_in[15];
  const float* W_query   = (const float*)d_in[16];
  const float* b_query   = (const float*)d_in[17];
  // d_in[18] W_key, d_in[19] b_key, d_in[21] b_W: no effect (a[q] cancels)
  const float* w_W       = (const float*)d_in[20];
  float* out = (float*)d_out;

  float* ws = (float*)d_ws;
  float* WT012 = ws;                    // 49152
  float* WLT   = ws + 49152;            // 16384
  float* WQT   = ws + 65536;            // 16384
  float* WIHT  = ws + 81920;            // 131072  [256][512]
  float* BIH   = ws + 212992;           // 512
  float* CPAD  = ws + 213504;           // 16
  float* E1    = ws + 213520;           // 65536
  float* G1    = ws + 279056;           // 65536
  float* E2    = ws + 344592;           // 65536
  float* Hfull = ws + 410128;           // 520192
  float* Cq    = ws + 930320;           // 4064
  int*   Pmaxi = (int*)(ws + 934384);   // 128
  int*   nselp = (int*)(ws + 934512);   // 4064
  unsigned long long* mwords =
      (unsigned long long*)(((uintptr_t)(ws + 938576) + 15) & ~(uintptr_t)15);
  int*   bar   = (int*)(ws + 955000);   // 128 ints (after mwords: 938576+16256=954832)

  k_zero<<<dim3(1), dim3(256), 0, stream>>>(bar, Pmaxi);
  k_fused<<<dim3(NBLK), dim3(256), 0, stream>>>(
      question, response, maskp, q_neighbors, s_neighbors, qs_table,
      emb_q, emb_s, emb_r, W_ih, b_ih, b_hh, W_agg, b_agg, W_last, b_last,
      W_query, b_query, w_W,
      WT012, WLT, WQT, WIHT, BIH, CPAD, E1, G1, E2, Hfull, Cq,
      Pmaxi, nselp, mwords, bar, out);
}

// Round 10
// 424.518 us; speedup vs baseline: 1.6513x; 1.6513x over previous
//
#include <hip/hip_runtime.h>
#include <stdint.h>

#define NB 32
#define SEQ 128
#define EMB 128
#define NSTEP 127
#define NS 512

__device__ __forceinline__ float ftanh(float x){ float e=__expf(2.f*x); return 1.f-2.f/(e+1.f); }
__device__ __forceinline__ float fsig(float x){ return 1.f/(1.f+__expf(-x)); }
__device__ __forceinline__ float4 ld4(const float* p){ return *(const float4*)p; }

// ---------------------------------------------------------------------------
// Streamed-WT GEMM: out[r,e] = bias[e] + sum_k X[r,k] * WT[k,e]
// X in LDS [R][XS]; WT global row-major [K][NEtot] (pre-transposed).
// Threads = 32 e-threads (4 e each) x R row-threads (1 row each).
// Works for 128-thr blocks (R=4) or 256-thr (R=8): rt = tid>>5.
// NAMED register double groups only — any VGPR array with non-constant index
// is demoted to scratch (round 5/6: 256 VGPR + 554 MB scratch traffic).
// ---------------------------------------------------------------------------
#define FMA4(acc, xv, a0, a1, a2, a3) \
  acc.x = fmaf(xv.x, a0.x, fmaf(xv.y, a1.x, fmaf(xv.z, a2.x, fmaf(xv.w, a3.x, acc.x)))); \
  acc.y = fmaf(xv.x, a0.y, fmaf(xv.y, a1.y, fmaf(xv.z, a2.y, fmaf(xv.w, a3.y, acc.y)))); \
  acc.z = fmaf(xv.x, a0.z, fmaf(xv.y, a1.z, fmaf(xv.z, a2.z, fmaf(xv.w, a3.z, acc.z)))); \
  acc.w = fmaf(xv.x, a0.w, fmaf(xv.y, a1.w, fmaf(xv.z, a2.w, fmaf(xv.w, a3.w, acc.w))));

template<int K, int XS>
__device__ __forceinline__ void gemm8(const float* __restrict__ WT, int NEtot,
                                      const float* Xl, const float* __restrict__ bias,
                                      float* outb)
{
  const int tid = threadIdx.x;
  const int et = tid & 31;
  const int rt = tid >> 5;
  const float* wp = WT + et*4;
  const float* xr = Xl + rt*XS;
  constexpr int G = K/4;
  float4 acc = {0.f,0.f,0.f,0.f};
  float4 w0 = ld4(wp);
  float4 w1 = ld4(wp + NEtot);
  float4 w2 = ld4(wp + 2*NEtot);
  float4 w3 = ld4(wp + 3*NEtot);
  const float* wq = wp + (size_t)4*NEtot;
  float4 m0 = ld4(wq);
  float4 m1 = ld4(wq + NEtot);
  float4 m2 = ld4(wq + 2*NEtot);
  float4 m3 = ld4(wq + 3*NEtot);
  #pragma unroll 2
  for (int g = 0; g + 2 < G; g += 2) {
    const float* wa = wp + (size_t)(4*(g+2))*NEtot;
    float4 n0 = ld4(wa);
    float4 n1 = ld4(wa + NEtot);
    float4 n2 = ld4(wa + 2*NEtot);
    float4 n3 = ld4(wa + 3*NEtot);
    float4 xa = ld4(xr + 4*g);
    FMA4(acc, xa, w0, w1, w2, w3);
    w0=n0; w1=n1; w2=n2; w3=n3;
    const float* wb = wp + (size_t)(4*(g+3))*NEtot;
    float4 o0 = ld4(wb);
    float4 o1 = ld4(wb + NEtot);
    float4 o2 = ld4(wb + 2*NEtot);
    float4 o3 = ld4(wb + 3*NEtot);
    float4 xb = ld4(xr + 4*(g+1));
    FMA4(acc, xb, m0, m1, m2, m3);
    m0=o0; m1=o1; m2=o2; m3=o3;
  }
  {
    float4 xa = ld4(xr + 4*(G-2));
    FMA4(acc, xa, w0, w1, w2, w3);
    float4 xb = ld4(xr + 4*(G-1));
    FMA4(acc, xb, m0, m1, m2, m3);
  }
  float4 bb = ld4(bias + et*4);
  acc.x+=bb.x; acc.y+=bb.y; acc.z+=bb.z; acc.w+=bb.w;
  *(float4*)(outb + rt*132 + et*4) = acc;
}

// ---------------------------------------------------------------------------
// k_T: transpose weights into ws, BIH = b_ih+b_hh, c_pad, zero G1/Pmaxi
// 512 blocks: the W_ih gather is uncoalesced -> needs the whole chip's TLP.
// ---------------------------------------------------------------------------
__global__ __launch_bounds__(256) void k_T(
    const float* __restrict__ W_agg, const float* __restrict__ W_last,
    const float* __restrict__ W_query, const float* __restrict__ W_ih,
    const float* __restrict__ b_ih, const float* __restrict__ b_hh,
    const float* __restrict__ b_query, const float* __restrict__ w_W,
    float* __restrict__ WT012, float* __restrict__ WLT, float* __restrict__ WQT,
    float* __restrict__ WIHT, float* __restrict__ BIH, float* __restrict__ CPAD,
    float* __restrict__ G1, int* __restrict__ Pmaxi)
{
  const int gid = blockIdx.x*256 + threadIdx.x;
  const int gsz = gridDim.x*256;
  for (int i = gid; i < 49152; i += gsz) {
    int j = i >> 14, rem = i & 16383, k = rem >> 7, e = rem & 127;
    WT012[i] = W_agg[j*16384 + e*128 + k];
  }
  for (int i = gid; i < 16384; i += gsz) {
    int k = i >> 7, e = i & 127;
    WLT[i] = W_last[e*128 + k];
    WQT[i] = W_query[e*128 + k];
  }
  for (int i = gid; i < 131072; i += gsz) {
    int k = i >> 9, e = i & 511;
    WIHT[i] = W_ih[e*256 + k];
  }
  for (int i = gid; i < 65536; i += gsz) G1[i] = 0.f;
  if (gid < 512) BIH[gid] = b_ih[gid] + b_hh[gid];
  if (gid < 128) Pmaxi[gid] = 0;
  if (blockIdx.x == 0) {
    __shared__ float red[256];
    float v = (threadIdx.x < 128) ? ftanh(b_query[threadIdx.x]) * w_W[128 + threadIdx.x] : 0.f;
    red[threadIdx.x] = v; __syncthreads();
    #pragma unroll
    for (int s = 128; s > 0; s >>= 1) {
      if (threadIdx.x < s) red[threadIdx.x] += red[threadIdx.x + s];
      __syncthreads();
    }
    if (threadIdx.x == 0) CPAD[0] = red[0];
  }
}

// ---------------------------------------------------------------------------
// k_pre: 128-thr blocks, 4 rows each. Blocks 0..127: E1 (4 s-rows).
// Blocks 128..1407: 4 of 5120 (s,j) level-2 pairs, atomicAdd into G1.
// ---------------------------------------------------------------------------
__global__ __launch_bounds__(128) void k_pre(
    const int* __restrict__ s_neighbors, const int* __restrict__ q_neighbors,
    const float* __restrict__ emb_q, const float* __restrict__ emb_s,
    const float* __restrict__ WT012, const float* __restrict__ b_agg,
    float* __restrict__ E1, float* __restrict__ G1)
{
  __shared__ float XA[4*132];
  __shared__ float XB[4*132];
  __shared__ int idx[40];
  __shared__ int n3[16];
  const int tid = threadIdx.x;
  const int blk = blockIdx.x;
  if (blk < 128) {
    const int s0 = blk*4;
    if (tid < 40) idx[tid] = s_neighbors[s0*10 + tid];
    __syncthreads();
    {
      int r = tid >> 5, e4 = (tid & 31) << 2;
      float4 a = ld4(emb_s + (size_t)(s0+r)*128 + e4);
      float sx=0,sy=0,sz=0,sw=0;
      #pragma unroll
      for (int jj = 0; jj < 10; ++jj) {
        float4 q = ld4(emb_q + (size_t)idx[r*10+jj]*128 + e4);
        sx+=q.x; sy+=q.y; sz+=q.z; sw+=q.w;
      }
      float4 o; o.x=a.x+0.1f*sx; o.y=a.y+0.1f*sy; o.z=a.z+0.1f*sz; o.w=a.w+0.1f*sw;
      *(float4*)(XA + r*132 + e4) = o;
    }
    __syncthreads();
    gemm8<128,132>(WT012 + 16384, 128, XA, b_agg + 128, XB);
    __syncthreads();
    for (int f = tid; f < 512; f += 128) {
      int r = f >> 7, e = f & 127;
      E1[(size_t)(s0+r)*128 + e] = ftanh(XB[r*132 + e]);
    }
  } else {
    const int p0 = (blk-128)*4;
    if (tid < 4) idx[tid] = s_neighbors[p0 + tid];
    __syncthreads();
    if (tid < 16) n3[tid] = q_neighbors[(size_t)idx[tid>>2]*4 + (tid&3)];
    __syncthreads();
    {
      int r = tid >> 5, e4 = (tid & 31) << 2;
      float4 a = ld4(emb_q + (size_t)idx[r]*128 + e4);
      float sx=0,sy=0,sz=0,sw=0;
      #pragma unroll
      for (int k = 0; k < 4; ++k) {
        float4 q = ld4(emb_s + (size_t)n3[r*4+k]*128 + e4);
        sx+=q.x; sy+=q.y; sz+=q.z; sw+=q.w;
      }
      float4 o; o.x=a.x+0.25f*sx; o.y=a.y+0.25f*sy; o.z=a.z+0.25f*sz; o.w=a.w+0.25f*sw;
      *(float4*)(XA + r*132 + e4) = o;
    }
    __syncthreads();
    gemm8<128,132>(WT012 + 32768, 128, XA, b_agg + 256, XB);
    __syncthreads();
    for (int f = tid; f < 512; f += 128) {
      int r = f >> 7, e = f & 127;
      atomicAdd(&G1[(size_t)((p0+r)/10)*128 + e], ftanh(XB[r*132 + e]));
    }
  }
}

// k_pre2: E2[s] = tanh((0.1*G1[s] + E1[s]) @ W1.T + b1)  (128 blocks x 4 rows)
__global__ __launch_bounds__(128) void k_pre2(
    const float* __restrict__ E1, const float* __restrict__ G1,
    const float* __restrict__ WT012, const float* __restrict__ b_agg,
    float* __restrict__ E2)
{
  __shared__ float XA[4*132];
  __shared__ float XB[4*132];
  const int tid = threadIdx.x;
  const int s0 = blockIdx.x*4;
  for (int f = tid; f < 512; f += 128) {
    int r = f >> 7, e = f & 127;
    XA[r*132 + e] = 0.1f*G1[(size_t)(s0+r)*128 + e] + E1[(size_t)(s0+r)*128 + e];
  }
  __syncthreads();
  gemm8<128,132>(WT012 + 16384, 128, XA, b_agg + 128, XB);
  __syncthreads();
  for (int f = tid; f < 512; f += 128) {
    int r = f >> 7, e = f & 127;
    E2[(size_t)(s0+r)*128 + e] = ftanh(XB[r*132 + e]);
  }
}

// ---------------------------------------------------------------------------
// k_chain: 1016 blocks x 128 thr x 4 (b,t)-rows: aggregation + LSTM h + Cq.
// 12.7 KB LDS + 2 waves/block -> ~24 resident waves/CU (vs 8 at 256-thr).
// ---------------------------------------------------------------------------
__global__ __launch_bounds__(128) void k_chain(
    const int* __restrict__ question, const int* __restrict__ response,
    const int* __restrict__ maskp, const int* __restrict__ q_neighbors,
    const float* __restrict__ emb_q, const float* __restrict__ emb_s,
    const float* __restrict__ emb_r,
    const float* __restrict__ WT012, const float* __restrict__ WLT,
    const float* __restrict__ WQT, const float* __restrict__ WIHT,
    const float* __restrict__ BIH,
    const float* __restrict__ b_agg, const float* __restrict__ b_last,
    const float* __restrict__ b_query, const float* __restrict__ w_W,
    const float* __restrict__ E1, const float* __restrict__ E2,
    float* __restrict__ Hfull, float* __restrict__ Cq)
{
  __shared__ float XA[4*132];
  __shared__ float XB[4*132];
  __shared__ float M1[4*132];
  __shared__ float M2[4*132];
  __shared__ float XC[4*264];
  __shared__ int qts[4], rts[4], mts[4], n1s[16];

  const int tid = threadIdx.x;
  const int blk = blockIdx.x;

  if (tid < 4) {
    int rid = blk*4 + tid;
    int b = rid / 127, t = rid - b*127;
    qts[tid] = question[b*SEQ + t];
    rts[tid] = response[b*SEQ + t];
    mts[tid] = maskp[b*SEQ + t];
  }
  __syncthreads();
  if (tid < 16) n1s[tid] = q_neighbors[(size_t)qts[tid>>2]*4 + (tid&3)];
  __syncthreads();
  // XA = emb_q[qt] + 0.25*sum emb_s[n1]; M1 = 0.25*sum E1[n1]; M2 = 0.25*sum E2[n1]
  {
    int r = tid >> 5, e4 = (tid & 31) << 2;
    const int* nn = n1s + r*4;
    float4 a = ld4(emb_q + (size_t)qts[r]*128 + e4);
    float s1x=0,s1y=0,s1z=0,s1w=0, s2x=0,s2y=0,s2z=0,s2w=0, s3x=0,s3y=0,s3z=0,s3w=0;
    #pragma unroll
    for (int i = 0; i < 4; ++i) {
      float4 q1 = ld4(emb_s + (size_t)nn[i]*128 + e4);
      float4 q2 = ld4(E1 + (size_t)nn[i]*128 + e4);
      float4 q3 = ld4(E2 + (size_t)nn[i]*128 + e4);
      s1x+=q1.x; s1y+=q1.y; s1z+=q1.z; s1w+=q1.w;
      s2x+=q2.x; s2y+=q2.y; s2z+=q2.z; s2w+=q2.w;
      s3x+=q3.x; s3y+=q3.y; s3z+=q3.z; s3w+=q3.w;
    }
    float4 o; o.x=a.x+0.25f*s1x; o.y=a.y+0.25f*s1y; o.z=a.z+0.25f*s1z; o.w=a.w+0.25f*s1w;
    *(float4*)(XA + r*132 + e4) = o;
    float4 p; p.x=0.25f*s2x; p.y=0.25f*s2y; p.z=0.25f*s2z; p.w=0.25f*s2w;
    *(float4*)(M1 + r*132 + e4) = p;
    float4 u; u.x=0.25f*s3x; u.y=0.25f*s3y; u.z=0.25f*s3z; u.w=0.25f*s3w;
    *(float4*)(M2 + r*132 + e4) = u;
  }
  // 3-stage aggregation chain
  __syncthreads();
  gemm8<128,132>(WT012, 128, XA, b_agg, XB);     // e0_1 pre-act
  __syncthreads();
  for (int f = tid; f < 528; f += 128) XB[f] = M1[f] + ftanh(XB[f]);
  __syncthreads();
  gemm8<128,132>(WT012, 128, XB, b_agg, XA);     // e0_2 pre-act
  __syncthreads();
  for (int f = tid; f < 528; f += 128) XA[f] = M2[f] + ftanh(XA[f]);
  __syncthreads();
  gemm8<128,132>(WT012, 128, XA, b_agg, XB);     // e0_3 pre-act
  __syncthreads();
  for (int f = tid; f < 528; f += 128) XB[f] = ftanh(XB[f]);
  __syncthreads();
  gemm8<128,132>(WLT, 128, XB, b_last, XA);      // agg pre-act
  __syncthreads();
  for (int f = tid; f < 512; f += 128) {
    int r = f >> 7, e = f & 127;
    float agg = ftanh(XA[r*132 + e]);
    XC[r*264 + e] = (mts[r] == 1) ? agg : emb_q[(size_t)qts[r]*128 + e];
    XC[r*264 + 128 + e] = emb_r[rts[r]*128 + e];
  }
  __syncthreads();
  // LSTM gates gi/gg/go (gf unused by the reference's h formula)
  gemm8<256,264>(WIHT,       512, XC, BIH,       XA);
  gemm8<256,264>(WIHT + 256, 512, XC, BIH + 256, XB);
  gemm8<256,264>(WIHT + 384, 512, XC, BIH + 384, M1);
  __syncthreads();
  for (int f = tid; f < 512; f += 128) {
    int r = f >> 7, e = f & 127;
    float gi = XA[r*132 + e], gg = XB[r*132 + e], go = M1[r*132 + e];
    float h = fsig(go) * ftanh(fsig(gi) * ftanh(gg));
    XC[r*264 + e] = h;
    Hfull[(size_t)(blk*4 + r)*128 + e] = h;
  }
  __syncthreads();
  gemm8<128,264>(WQT, 128, XC, b_query, XA);     // c pre-act
  __syncthreads();
  {
    const int et = tid & 31, rt = tid >> 5;
    float4 o = ld4(XA + rt*132 + et*4);
    float4 wv = ld4(w_W + 128 + et*4);
    float s = ftanh(o.x)*wv.x + ftanh(o.y)*wv.y + ftanh(o.z)*wv.z + ftanh(o.w)*wv.w;
    #pragma unroll
    for (int off = 16; off > 0; off >>= 1) s += __shfl_down(s, off);
    if (et == 0) Cq[blk*4 + rt] = s;
  }
}

// ---------------------------------------------------------------------------
// k_match: one wave per (t, b): masks + nsel; Pmax[t] via atomicMax
// ---------------------------------------------------------------------------
__global__ __launch_bounds__(64) void k_match(
    const int* __restrict__ question, const int* __restrict__ q_neighbors,
    const int* __restrict__ s_neighbors,
    int* __restrict__ nsel, unsigned long long* __restrict__ mwords,
    int* __restrict__ Pmaxi)
{
  __shared__ int qr[40];
  const int tid = threadIdx.x;
  const int t = blockIdx.x;
  const int b = blockIdx.y;
  const int q_next = question[b*SEQ + t + 1];
  if (tid < 40)
    qr[tid] = s_neighbors[(size_t)q_neighbors[(size_t)q_next*4 + tid/10]*10 + tid%10];
  __syncthreads();
  int q0 = question[b*SEQ + tid];
  int q1 = question[b*SEQ + 64 + tid];
  bool p0 = false, p1 = false;
  #pragma unroll 8
  for (int i = 0; i < 40; ++i) { p0 |= (q0 == qr[i]); p1 |= (q1 == qr[i]); }
  p0 &= (tid < t);
  p1 &= (64 + tid < t);
  unsigned long long w0 = __ballot(p0);
  unsigned long long w1 = __ballot(p1);
  if (tid == 0) {
    mwords[((size_t)b*NSTEP + t)*2 + 0] = w0;
    mwords[((size_t)b*NSTEP + t)*2 + 1] = w1;
    int ns = __popcll(w0) + __popcll(w1);
    nsel[b*NSTEP + t] = ns;
    atomicMax(&Pmaxi[t], ns);
  }
}

__device__ __forceinline__ float wredsum(float v) {
  #pragma unroll
  for (int o = 32; o > 0; o >>= 1) v += __shfl_down(v, o);
  return v;
}
__device__ __forceinline__ float wredmax(float v) {
  #pragma unroll
  for (int o = 32; o > 0; o >>= 1) v = fmaxf(v, __shfl_down(v, o));
  return v;
}

// ---------------------------------------------------------------------------
// k_attn: collapsed attention (a[q] cancels across the softmax), y -> out
// ---------------------------------------------------------------------------
__global__ __launch_bounds__(128) void k_attn(
    const int* __restrict__ question, const float* __restrict__ qs_table,
    const float* __restrict__ emb_q, const float* __restrict__ emb_s,
    const float* __restrict__ CPAD,
    const float* __restrict__ Hfull, const float* __restrict__ Cq,
    const int* __restrict__ nsel, const unsigned long long* __restrict__ mwords,
    const int* __restrict__ Pmaxi, float* __restrict__ out)
{
  __shared__ float us[128];
  __shared__ int cols[8];
  __shared__ int cnt;
  __shared__ float smx[2];
  __shared__ float s3[2][3];
  const int tid = threadIdx.x;
  const int wid = tid >> 6;
  const int bid = blockIdx.x;
  const int b = bid / NSTEP, t = bid % NSTEP;
  const size_t bt = (size_t)b*NSTEP + t;
  const int q_next = question[b*SEQ + t + 1];

  if (tid == 0) cnt = 0;
  __syncthreads();
  {
    float4 v = ld4(qs_table + (size_t)q_next*NS + tid*4);
    if (v.x > 0.f) { int p = atomicAdd(&cnt, 1); if (p < 8) cols[p] = tid*4; }
    if (v.y > 0.f) { int p = atomicAdd(&cnt, 1); if (p < 8) cols[p] = tid*4+1; }
    if (v.z > 0.f) { int p = atomicAdd(&cnt, 1); if (p < 8) cols[p] = tid*4+2; }
    if (v.w > 0.f) { int p = atomicAdd(&cnt, 1); if (p < 8) cols[p] = tid*4+3; }
  }
  __syncthreads();
  const int nc = min(cnt, 4);
  {
    float ue = emb_q[(size_t)q_next*EMB + tid];
    for (int i = 0; i < nc; ++i) ue += emb_s[(size_t)cols[i]*EMB + tid];
    us[tid] = ue;
  }
  const float c_pad = CPAD[0];
  const float P = (float)(Pmaxi[t] - nsel[bt]);

  const unsigned long long w0 = mwords[bt*2 + 0];
  const unsigned long long w1 = mwords[bt*2 + 1];
  const bool matched = (tid < 64) ? ((w0 >> tid) & 1ull)
                                  : ((w1 >> (tid - 64)) & 1ull);
  const float c_cur = Cq[bt];
  float Cp = matched ? ((tid == 0) ? c_pad : Cq[(size_t)b*NSTEP + tid]) : -3.0e38f;
  float mh = wredmax(Cp);
  if ((tid & 63) == 0) smx[wid] = mh;
  __syncthreads();   // also publishes us[]
  float M = fmaxf(fmaxf(smx[0], smx[1]), fmaxf(c_cur, c_pad));
  float wgt = matched ? __expf(Cp - M) : 0.f;
  float dotp = 0.f;
  if (matched && tid >= 1) {  // p=0 history row is zeros
    const float* hp = Hfull + ((size_t)b*NSTEP + tid)*EMB;
    float s = 0.f;
    #pragma unroll 8
    for (int e = 0; e < 128; e += 4) {
      float4 h4 = ld4(hp + e);
      s = fmaf(us[e],h4.x, fmaf(us[e+1],h4.y, fmaf(us[e+2],h4.z, fmaf(us[e+3],h4.w, s))));
    }
    dotp = s;
  }
  float gcp = us[tid] * Hfull[bt*EMB + tid];
  float a0 = wredsum(wgt);
  float a1 = wredsum(wgt * dotp);
  float a2 = wredsum(gcp);
  if ((tid & 63) == 0) { s3[wid][0] = a0; s3[wid][1] = a1; s3[wid][2] = a2; }
  __syncthreads();
  if (tid == 0) {
    float Sexp = s3[0][0] + s3[1][0];
    float Snum = s3[0][1] + s3[1][1];
    float gc   = s3[0][2] + s3[1][2];
    float Ec = __expf(c_cur - M), Ep = __expf(c_pad - M);
    float D = Sexp + Ec + P * Ep;
    float numt = Snum + Ec * gc;
    out[b*SEQ + t + 1] = fsig(numt / D);
    if (t == 0) out[b*SEQ] = 0.5f;
  }
}

extern "C" void kernel_launch(void* const* d_in, const int* in_sizes, int n_in,
                              void* d_out, int out_size, void* d_ws, size_t ws_size,
                              hipStream_t stream) {
  const int* question    = (const int*)d_in[0];
  const int* response    = (const int*)d_in[1];
  const int* maskp       = (const int*)d_in[2];
  const int* q_neighbors = (const int*)d_in[3];
  const int* s_neighbors = (const int*)d_in[4];
  const float* qs_table  = (const float*)d_in[5];
  const float* emb_q     = (const float*)d_in[6];
  const float* emb_s     = (const float*)d_in[7];
  const float* emb_r     = (const float*)d_in[8];
  const float* W_ih      = (const float*)d_in[9];
  const float* b_ih      = (const float*)d_in[10];
  const float* b_hh      = (const float*)d_in[11];
  const float* W_agg     = (const float*)d_in[12];
  const float* b_agg     = (const float*)d_in[13];
  const float* W_last    = (const float*)d_in[14];
  const float* b_last    = (const float*)d_in[15];
  const float* W_query   = (const float*)d_in[16];
  const float* b_query   = (const float*)d_in[17];
  // d_in[18] W_key, d_in[19] b_key, d_in[21] b_W: no effect (a[q] cancels)
  const float* w_W       = (const float*)d_in[20];
  float* out = (float*)d_out;

  float* ws = (float*)d_ws;
  float* WT012 = ws;                    // 49152
  float* WLT   = ws + 49152;            // 16384
  float* WQT   = ws + 65536;            // 16384
  float* WIHT  = ws + 81920;            // 131072  [256][512]
  float* BIH   = ws + 212992;           // 512
  float* CPAD  = ws + 213504;           // 16
  float* E1    = ws + 213520;           // 65536
  float* G1    = ws + 279056;           // 65536
  float* E2    = ws + 344592;           // 65536
  float* Hfull = ws + 410128;           // 520192
  float* Cq    = ws + 930320;           // 4064
  int*   Pmaxi = (int*)(ws + 934384);   // 128
  int*   nselp = (int*)(ws + 934512);   // 4064
  unsigned long long* mwords =
      (unsigned long long*)(((uintptr_t)(ws + 938576) + 15) & ~(uintptr_t)15);

  k_T<<<dim3(512), dim3(256), 0, stream>>>(
      W_agg, W_last, W_query, W_ih, b_ih, b_hh, b_query, w_W,
      WT012, WLT, WQT, WIHT, BIH, CPAD, G1, Pmaxi);
  k_pre<<<dim3(1408), dim3(128), 0, stream>>>(
      s_neighbors, q_neighbors, emb_q, emb_s, WT012, b_agg, E1, G1);
  k_pre2<<<dim3(128), dim3(128), 0, stream>>>(E1, G1, WT012, b_agg, E2);
  k_chain<<<dim3(1016), dim3(128), 0, stream>>>(
      question, response, maskp, q_neighbors, emb_q, emb_s, emb_r,
      WT012, WLT, WQT, WIHT, BIH, b_agg, b_last, b_query, w_W,
      E1, E2, Hfull, Cq);
  k_match<<<dim3(NSTEP, NB), dim3(64), 0, stream>>>(
      question, q_neighbors, s_neighbors, nselp, mwords, Pmaxi);
  k_attn<<<dim3(NB*NSTEP), dim3(128), 0, stream>>>(
      question, qs_table, emb_q, emb_s, CPAD, Hfull, Cq,
      nselp, mwords, Pmaxi, out);
}